// Round 1
// baseline (120.794 us; speedup 1.0000x reference)
//
#include <hip/hip_runtime.h>
#include <math.h>

constexpr int B_ = 4, C_ = 32, L_ = 256, M_ = 256, F_ = 8, N_ = 64;

__global__ __launch_bounds__(256) void sphereconv_kernel(
    const float* __restrict__ xr, const float* __restrict__ xi,
    const float* __restrict__ wr, const float* __restrict__ wi,
    float* __restrict__ out)
{
    // interpolated weights for this l: [c][f], f-contiguous so we can read float4
    __shared__ float4 ws_r[C_ * 2];
    __shared__ float4 ws_i[C_ * 2];

    const int b = blockIdx.x / L_;
    const int l = blockIdx.x % L_;
    const int m = threadIdx.x;

    // interp coords (uniform across block): t = l/(L-1)*(N-1)
    const float t = ((float)l / (float)(L_ - 1)) * (float)(N_ - 1);
    int lo = (int)floorf(t);
    if (lo > N_ - 2) lo = N_ - 2;
    const float frac = t - (float)lo;

    // each of the 256 threads computes one (c,f) weight pair
    {
        const int idx = threadIdx.x;          // 0..255 == C_*F_
        const int c = idx >> 3, f = idx & 7;
        const int base = (f * C_ + c) * N_ + lo;   // w layout (F,C,N,1)
        ((float*)ws_r)[c * F_ + f] = wr[base] * (1.0f - frac) + wr[base + 1] * frac;
        ((float*)ws_i)[c * F_ + f] = wi[base] * (1.0f - frac) + wi[base + 1] * frac;
    }
    __syncthreads();

    float4 ar = {0.f,0.f,0.f,0.f}, br = {0.f,0.f,0.f,0.f};   // real acc f0-3, f4-7
    float4 ai = {0.f,0.f,0.f,0.f}, bi = {0.f,0.f,0.f,0.f};   // imag acc

    const size_t strideC = (size_t)L_ * M_;
    const size_t xoff = (size_t)b * C_ * strideC + (size_t)l * M_ + m;
    const float* xrp = xr + xoff;
    const float* xip = xi + xoff;

#pragma unroll 8
    for (int c = 0; c < C_; ++c) {
        const float vr = xrp[(size_t)c * strideC];
        const float vi = xip[(size_t)c * strideC];
        const float4 w0 = ws_r[c * 2 + 0];
        const float4 w1 = ws_r[c * 2 + 1];
        const float4 u0 = ws_i[c * 2 + 0];
        const float4 u1 = ws_i[c * 2 + 1];
        ar.x += w0.x * vr - u0.x * vi;  ai.x += w0.x * vi + u0.x * vr;
        ar.y += w0.y * vr - u0.y * vi;  ai.y += w0.y * vi + u0.y * vr;
        ar.z += w0.z * vr - u0.z * vi;  ai.z += w0.z * vi + u0.z * vr;
        ar.w += w0.w * vr - u0.w * vi;  ai.w += w0.w * vi + u0.w * vr;
        br.x += w1.x * vr - u1.x * vi;  bi.x += w1.x * vi + u1.x * vr;
        br.y += w1.y * vr - u1.y * vi;  bi.y += w1.y * vi + u1.y * vr;
        br.z += w1.z * vr - u1.z * vi;  bi.z += w1.z * vi + u1.z * vr;
        br.w += w1.w * vr - u1.w * vi;  bi.w += w1.w * vi + u1.w * vr;
    }

    const float scale = sqrtf(1.0f + (float)l) * (1.0f / (float)C_);
    const float accr[F_] = {ar.x, ar.y, ar.z, ar.w, br.x, br.y, br.z, br.w};
    const float acci[F_] = {ai.x, ai.y, ai.z, ai.w, bi.x, bi.y, bi.z, bi.w};

    // out layout: ((s*B + b)*F + f)*L + l)*M + m ; s=0 real(relu), s=1 imag
    const size_t o0 = (((size_t)b * F_) * L_ + l) * M_ + m;
    const size_t imagOff = (size_t)B_ * F_ * L_ * M_;
#pragma unroll
    for (int f = 0; f < F_; ++f) {
        float yr = accr[f] * scale;
        yr = fmaxf(yr, 0.0f);
        const float yi = acci[f] * scale;
        out[o0 + (size_t)f * strideC] = yr;
        out[o0 + (size_t)f * strideC + imagOff] = yi;
    }
}

extern "C" void kernel_launch(void* const* d_in, const int* in_sizes, int n_in,
                              void* d_out, int out_size, void* d_ws, size_t ws_size,
                              hipStream_t stream) {
    const float* xr = (const float*)d_in[0];
    const float* xi = (const float*)d_in[1];
    const float* wr = (const float*)d_in[2];
    const float* wi = (const float*)d_in[3];
    float* out = (float*)d_out;
    sphereconv_kernel<<<dim3(B_ * L_), dim3(256), 0, stream>>>(xr, xi, wr, wi, out);
}